// Round 1
// baseline (5506.191 us; speedup 1.0000x reference)
//
#include <hip/hip_runtime.h>
#include <hip/hip_bf16.h>

// Problem constants
// B=64, P=196, T=30, E=D=A=ENC=512, V=30000
#define BB 64
#define PP 196
#define TT 30
#define DD 512
#define VV 30000
#define VPAD 30080           // 235*128
#define MROWS 1856           // 29*64
#define MPAD 1920            // 15*128

typedef __attribute__((ext_vector_type(8))) short short8;
typedef __attribute__((ext_vector_type(4))) float f32x4;

__device__ __forceinline__ unsigned short f2bf(float f) {
    unsigned int u = __float_as_uint(f);
    unsigned int r = u + 0x7FFFu + ((u >> 16) & 1u);
    return (unsigned short)(r >> 16);
}
__device__ __forceinline__ float sigf(float x) { return 1.f / (1.f + __expf(-x)); }
__device__ __forceinline__ float tanh_fast(float x) { return 1.f - 2.f / (1.f + __expf(2.f * x)); }

// ---------------- cast fp32 -> bf16 (same layout) ----------------
__global__ __launch_bounds__(256) void k_cast(const float* __restrict__ in,
                                              unsigned short* __restrict__ out, int n) {
    int i = blockIdx.x * 256 + threadIdx.x;
    int stride = gridDim.x * 256;
    for (; i < n; i += stride) out[i] = f2bf(in[i]);
}

// ------------- transpose fp32 [R][C] -> bf16 [Cpad][R], zero-fill rows C..Cpad -------------
__global__ __launch_bounds__(256) void k_transpose_cast(const float* __restrict__ in,
                                                        unsigned short* __restrict__ out,
                                                        int R, int C, int Cpad) {
    __shared__ float tile[32][33];
    int tx = threadIdx.x & 31, ty = threadIdx.x >> 5;  // 32 x 8
    int c0 = blockIdx.x * 32, r0 = blockIdx.y * 32;
#pragma unroll
    for (int i = 0; i < 4; ++i) {
        int r = r0 + ty + i * 8, c = c0 + tx;
        tile[ty + i * 8][tx] = (c < C) ? in[(size_t)r * C + c] : 0.f;
    }
    __syncthreads();
#pragma unroll
    for (int i = 0; i < 4; ++i) {
        int outr = c0 + ty + i * 8, outc = r0 + tx;
        if (outr < Cpad) out[(size_t)outr * R + outc] = f2bf(tile[tx][ty + i * 8]);
    }
}

// ---------------- zero out[:, 0, :] ----------------
__global__ __launch_bounds__(256) void k_zero0(float* __restrict__ out) {
    int i = blockIdx.x * 256 + threadIdx.x;  // 64*30000 = 1,920,000 exact
    int b = i / VV, v = i - b * VV;
    out[(size_t)b * (TT * VV) + v] = 0.f;
}

// ---------------- init h0, c0 ----------------
// grid 128: b = blockIdx>>1, which = blockIdx&1 (0->h into xh[:,1024:], 1->c)
__global__ __launch_bounds__(256) void k_init(const float* __restrict__ pooled,
                                              const float* __restrict__ Wh, const float* __restrict__ bh,
                                              const float* __restrict__ Wc, const float* __restrict__ bc,
                                              float* __restrict__ xh, float* __restrict__ cbuf) {
    int b = blockIdx.x >> 1, which = blockIdx.x & 1, t = threadIdx.x;
    const float* W = which ? Wc : Wh;
    const float* bias = which ? bc : bh;
    const float* pr = pooled + b * DD;
    float a0 = 0.f, a1 = 0.f;
#pragma unroll 4
    for (int k = 0; k < DD; ++k) {
        float pv = pr[k];
        a0 += pv * W[k * DD + t];
        a1 += pv * W[k * DD + t + 256];
    }
    float v0 = tanh_fast(a0 + bias[t]);
    float v1 = tanh_fast(a1 + bias[t + 256]);
    if (which == 0) {
        xh[b * 1536 + 1024 + t] = v0;
        xh[b * 1536 + 1024 + t + 256] = v1;
    } else {
        cbuf[b * DD + t] = v0;
        cbuf[b * DD + t + 256] = v1;
    }
}

// ---------------- per step: dec_proj = h@Wd + bd ; beta = sigmoid(h@Wb + bb) ----------------
// grid 64 blocks x 256 thr: colg = blockIdx*16 + (t&15) in [0,1024); t>>4 = b-group (4 b's each)
__global__ __launch_bounds__(256) void k_decbeta(const float* __restrict__ xh,
                                                 const float* __restrict__ Wd, const float* __restrict__ bd,
                                                 const float* __restrict__ Wb, const float* __restrict__ bb,
                                                 float* __restrict__ decp, float* __restrict__ betab) {
    int t = threadIdx.x;
    int colg = blockIdx.x * 16 + (t & 15);
    int bg = t >> 4;
    bool isBeta = colg >= DD;
    int col = colg & (DD - 1);
    const float* W = isBeta ? Wb : Wd;
    float acc0 = 0.f, acc1 = 0.f, acc2 = 0.f, acc3 = 0.f;
    const float* h0 = xh + (bg * 4 + 0) * 1536 + 1024;
    const float* h1 = xh + (bg * 4 + 1) * 1536 + 1024;
    const float* h2 = xh + (bg * 4 + 2) * 1536 + 1024;
    const float* h3 = xh + (bg * 4 + 3) * 1536 + 1024;
#pragma unroll 4
    for (int k = 0; k < DD; ++k) {
        float wv = W[k * DD + col];
        acc0 += h0[k] * wv;
        acc1 += h1[k] * wv;
        acc2 += h2[k] * wv;
        acc3 += h3[k] * wv;
    }
    float bias = isBeta ? bb[col] : bd[col];
    float r[4] = {acc0 + bias, acc1 + bias, acc2 + bias, acc3 + bias};
    float* dst = isBeta ? betab : decp;
#pragma unroll
    for (int i = 0; i < 4; ++i) {
        float v = r[i];
        if (isBeta) v = sigf(v);
        dst[(bg * 4 + i) * DD + col] = v;
    }
}

// ---------------- per step: attention scores -> softmax -> ctx -> x = [emb, gate*ctx] ----------------
// grid 64 (one block per b), 256 threads (4 waves)
__global__ __launch_bounds__(256) void k_attn(const float* __restrict__ ep,
                                              const float* __restrict__ feats,
                                              const float* __restrict__ decp,
                                              const float* __restrict__ betab,
                                              const float* __restrict__ wf,
                                              const int* __restrict__ captions,
                                              const float* __restrict__ emb_table,
                                              float* __restrict__ xh, int tstep) {
    int b = blockIdx.x, t = threadIdx.x;
    int lane = t & 63, wave = t >> 6;
    __shared__ float dec_s[DD], wf_s[DD], sc_s[256], red_s[256];
    dec_s[t] = decp[b * DD + t];
    dec_s[t + 256] = decp[b * DD + t + 256];
    wf_s[t] = wf[t];
    wf_s[t + 256] = wf[t + 256];
    __syncthreads();

    const float* epb = ep + (size_t)(b * PP) * DD;
    for (int p = wave; p < PP; p += 4) {
        const float* row = epb + p * DD;
        float s = 0.f;
#pragma unroll
        for (int j = 0; j < 8; ++j) {
            int a = lane + j * 64;
            float v = row[a] + dec_s[a];
            s += tanh_fast(v) * wf_s[a];
        }
        for (int off = 32; off; off >>= 1) s += __shfl_xor(s, off);
        if (lane == 0) sc_s[p] = s;
    }
    __syncthreads();

    // softmax over 196
    float sv = (t < PP) ? sc_s[t] : -1e30f;
    red_s[t] = sv;
    __syncthreads();
    for (int off = 128; off; off >>= 1) {
        if (t < off) red_s[t] = fmaxf(red_s[t], red_s[t + off]);
        __syncthreads();
    }
    float mx = red_s[0];
    __syncthreads();
    float e = (t < PP) ? __expf(sv - mx) : 0.f;
    red_s[t] = e;
    __syncthreads();
    for (int off = 128; off; off >>= 1) {
        if (t < off) red_s[t] += red_s[t + off];
        __syncthreads();
    }
    float denom = red_s[0];
    __syncthreads();
    if (t < PP) sc_s[t] = e / denom;  // alpha
    __syncthreads();

    // ctx (each thread handles d=t and d=t+256)
    const float* fb = feats + (size_t)(b * PP) * DD;
    float c0 = 0.f, c1 = 0.f;
#pragma unroll 2
    for (int p = 0; p < PP; ++p) {
        float a = sc_s[p];
        c0 += a * fb[p * DD + t];
        c1 += a * fb[p * DD + t + 256];
    }
    float g0 = betab[b * DD + t], g1 = betab[b * DD + t + 256];
    int tok = captions[b * TT + (tstep - 1)];
    const float* er = emb_table + (size_t)tok * DD;
    float* xrow = xh + b * 1536;
    xrow[t] = er[t];
    xrow[t + 256] = er[t + 256];
    xrow[512 + t] = g0 * c0;
    xrow[768 + t] = g1 * c1;
}

// ---------------- per step: gates = [x,h] @ [W_ih;W_hh] (+biases on khalf 0) ----------------
// grid (128, 2): x = j-tile of 16 cols, y = K-half. 256 thr: col=t&15, rows=(t>>4)*4+i
__global__ __launch_bounds__(256) void k_gates(const float* __restrict__ xh,
                                               const float* __restrict__ W_ih,
                                               const float* __restrict__ W_hh,
                                               const float* __restrict__ b_ih,
                                               const float* __restrict__ b_hh,
                                               float* __restrict__ gates) {
    __shared__ float As[64][33];
    __shared__ float Bs[32][17];
    int t = threadIdx.x;
    int j0 = blockIdx.x * 16;
    int khalf = blockIdx.y;
    int colt = t & 15, rg = t >> 4;
    float acc[4] = {0.f, 0.f, 0.f, 0.f};
    int kend = khalf * 768 + 768;
    for (int k0 = khalf * 768; k0 < kend; k0 += 32) {
#pragma unroll
        for (int i = 0; i < 2; ++i) {
            int u = t + i * 256;
            int row = u >> 3, c4 = (u & 7) * 4;
            const float4 v = *(const float4*)(xh + row * 1536 + k0 + c4);
            As[row][c4] = v.x; As[row][c4 + 1] = v.y; As[row][c4 + 2] = v.z; As[row][c4 + 3] = v.w;
        }
#pragma unroll
        for (int i = 0; i < 2; ++i) {
            int u = t + i * 256;
            int kk = u >> 4, c = u & 15;
            int kg = k0 + kk;
            const float* Wrow = (kg < 1024) ? (W_ih + (size_t)kg * 2048) : (W_hh + (size_t)(kg - 1024) * 2048);
            Bs[kk][c] = Wrow[j0 + c];
        }
        __syncthreads();
#pragma unroll
        for (int kk = 0; kk < 32; ++kk) {
            float bv = Bs[kk][colt];
#pragma unroll
            for (int i = 0; i < 4; ++i) acc[i] += As[rg * 4 + i][kk] * bv;
        }
        __syncthreads();
    }
    int j = j0 + colt;
    float bsum = (khalf == 0) ? (b_ih[j] + b_hh[j]) : 0.f;
    float* dst = gates + khalf * (64 * 2048);
#pragma unroll
    for (int i = 0; i < 4; ++i) dst[(rg * 4 + i) * 2048 + j] = acc[i] + bsum;
}

// ---------------- per step: LSTM pointwise ----------------
__global__ __launch_bounds__(256) void k_lstm(const float* __restrict__ gates,
                                              float* __restrict__ cbuf, float* __restrict__ xh,
                                              unsigned short* __restrict__ hb, int tstep) {
    int idx = blockIdx.x * 256 + threadIdx.x;  // 32768
    int b = idx >> 9, d = idx & 511;
    const float* g0 = gates + b * 2048;
    const float* g1 = gates + 64 * 2048 + b * 2048;
    float gi = sigf(g0[d] + g1[d]);
    float gf = sigf(g0[d + 512] + g1[d + 512]);
    float gg = tanh_fast(g0[d + 1024] + g1[d + 1024]);
    float go = sigf(g0[d + 1536] + g1[d + 1536]);
    float cn = gf * cbuf[idx] + gi * gg;
    float hn = go * tanh_fast(cn);
    cbuf[idx] = cn;
    xh[b * 1536 + 1024 + d] = hn;
    hb[((tstep - 1) * 64 + b) * DD + d] = f2bf(hn);
}

// ---------------- bf16 MFMA GEMM: C = A[M][512] * Bt[N][512]^T (+bias) ----------------
// MODE 0: enc_proj -> C[m][512] fp32, bias be_att (M=12544, N=512, exact tiles)
// MODE 1: vocab    -> scatter C[b][t+1][v], bias b_fc, guards (M=1920 pad, N=30080 pad)
template <int MODE>
__global__ __launch_bounds__(256) void gemm_mfma(const unsigned short* __restrict__ A,
                                                 const unsigned short* __restrict__ Bt,
                                                 const float* __restrict__ bias,
                                                 float* __restrict__ C) {
    constexpr int K = 512;
    __shared__ unsigned short As[128 * 32];
    __shared__ unsigned short Bs[128 * 32];
    const int t = threadIdx.x;
    const int m0 = blockIdx.y * 128;
    const int n0 = blockIdx.x * 128;
    const int lane = t & 63, wave = t >> 6;
    const int wm = wave >> 1, wn = wave & 1;
    const int r16 = lane & 15, kg = lane >> 4;
    const int swz = kg ^ ((r16 >> 1) & 3);

    f32x4 acc[4][4];
#pragma unroll
    for (int i = 0; i < 4; ++i)
#pragma unroll
        for (int j = 0; j < 4; ++j) acc[i][j] = {0.f, 0.f, 0.f, 0.f};

    const short8* As8 = (const short8*)As;
    const short8* Bs8 = (const short8*)Bs;

    for (int k0 = 0; k0 < K; k0 += 32) {
#pragma unroll
        for (int i = 0; i < 2; ++i) {
            int u = t + i * 256;
            int row = u >> 2, cs = u & 3;
            int csrc = cs ^ ((row >> 1) & 3);
            ((uint4*)As)[u] = *(const uint4*)(A + (size_t)(m0 + row) * K + k0 + csrc * 8);
            ((uint4*)Bs)[u] = *(const uint4*)(Bt + (size_t)(n0 + row) * K + k0 + csrc * 8);
        }
        __syncthreads();
        short8 af[4], bfr[4];
#pragma unroll
        for (int i = 0; i < 4; ++i) af[i] = As8[(wm * 64 + i * 16 + r16) * 4 + swz];
#pragma unroll
        for (int j = 0; j < 4; ++j) bfr[j] = Bs8[(wn * 64 + j * 16 + r16) * 4 + swz];
#pragma unroll
        for (int i = 0; i < 4; ++i)
#pragma unroll
            for (int j = 0; j < 4; ++j)
                acc[i][j] = __builtin_amdgcn_mfma_f32_16x16x32_bf16(af[i], bfr[j], acc[i][j], 0, 0, 0);
        __syncthreads();
    }

#pragma unroll
    for (int i = 0; i < 4; ++i) {
#pragma unroll
        for (int j = 0; j < 4; ++j) {
            int colg = n0 + wn * 64 + j * 16 + r16;
            float bv;
            if (MODE == 0) bv = bias[colg];
            else bv = (colg < VV) ? bias[colg] : 0.f;
#pragma unroll
            for (int r = 0; r < 4; ++r) {
                int rowg = m0 + wm * 64 + i * 16 + kg * 4 + r;
                float v = acc[i][j][r] + bv;
                if (MODE == 0) {
                    C[(size_t)rowg * 512 + colg] = v;
                } else {
                    if (rowg < MROWS && colg < VV) {
                        int tt = rowg >> 6, bb2 = rowg & 63;
                        C[(size_t)bb2 * (TT * VV) + (size_t)(tt + 1) * VV + colg] = v;
                    }
                }
            }
        }
    }
}

extern "C" void kernel_launch(void* const* d_in, const int* in_sizes, int n_in,
                              void* d_out, int out_size, void* d_ws, size_t ws_size,
                              hipStream_t stream) {
    const float* feats   = (const float*)d_in[0];
    const float* pooled  = (const float*)d_in[1];
    const int*   caps    = (const int*)d_in[2];
    const float* We      = (const float*)d_in[3];
    const float* be      = (const float*)d_in[4];
    const float* Wd      = (const float*)d_in[5];
    const float* bd      = (const float*)d_in[6];
    const float* wfv     = (const float*)d_in[7];
    const float* emb     = (const float*)d_in[9];
    const float* W_ih    = (const float*)d_in[10];
    const float* W_hh    = (const float*)d_in[11];
    const float* b_ih    = (const float*)d_in[12];
    const float* b_hh    = (const float*)d_in[13];
    const float* W_inh   = (const float*)d_in[14];
    const float* b_inh   = (const float*)d_in[15];
    const float* W_inc   = (const float*)d_in[16];
    const float* b_inc   = (const float*)d_in[17];
    const float* Wfc     = (const float*)d_in[18];
    const float* bfc     = (const float*)d_in[19];
    const float* Wbeta   = (const float*)d_in[20];
    const float* bbeta   = (const float*)d_in[21];
    float* out = (float*)d_out;

    char* ws = (char*)d_ws;
    size_t off = 0;
    auto alloc = [&](size_t bytes) -> char* {
        char* p = ws + off;
        off += (bytes + 255) & ~(size_t)255;
        return p;
    };
    float*          ep    = (float*)alloc((size_t)12544 * 512 * 4);          // enc_proj fp32
    unsigned short* fb    = (unsigned short*)alloc((size_t)12544 * 512 * 2); // feats bf16
    unsigned short* WeT   = (unsigned short*)alloc((size_t)512 * 512 * 2);   // We^T bf16
    unsigned short* WfcT  = (unsigned short*)alloc((size_t)VPAD * 512 * 2);  // Wfc^T bf16 (padded)
    unsigned short* hb    = (unsigned short*)alloc((size_t)MPAD * 512 * 2);  // h_all bf16 (padded)
    float*          xh    = (float*)alloc((size_t)64 * 1536 * 4);            // [x(1024) | h(512)] per b
    float*          cb    = (float*)alloc((size_t)64 * 512 * 4);
    float*          decp  = (float*)alloc((size_t)64 * 512 * 4);
    float*          betab = (float*)alloc((size_t)64 * 512 * 4);
    float*          gates = (float*)alloc((size_t)2 * 64 * 2048 * 4);        // 2 K-halves
    (void)ws_size; (void)in_sizes; (void)n_in; (void)out_size;

    // precompute
    k_cast<<<2048, 256, 0, stream>>>(feats, fb, 12544 * 512);
    k_transpose_cast<<<dim3(16, 16), 256, 0, stream>>>(We, WeT, 512, 512, 512);
    k_transpose_cast<<<dim3(940, 16), 256, 0, stream>>>(Wfc, WfcT, 512, VV, VPAD);
    k_init<<<128, 256, 0, stream>>>(pooled, W_inh, b_inh, W_inc, b_inc, xh, cb);
    gemm_mfma<0><<<dim3(4, 98), 256, 0, stream>>>(fb, WeT, be, ep);
    k_zero0<<<7500, 256, 0, stream>>>(out);

    // recurrence
    for (int t = 1; t < TT; ++t) {
        k_decbeta<<<64, 256, 0, stream>>>(xh, Wd, bd, Wbeta, bbeta, decp, betab);
        k_attn<<<64, 256, 0, stream>>>(ep, feats, decp, betab, wfv, caps, emb, xh, t);
        k_gates<<<dim3(128, 2), 256, 0, stream>>>(xh, W_ih, W_hh, b_ih, b_hh, gates);
        k_lstm<<<128, 256, 0, stream>>>(gates, cb, xh, hb, t);
    }

    // batched vocab projection for all 29 steps
    gemm_mfma<1><<<dim3(235, 15), 256, 0, stream>>>(hb, WfcT, bfc, out);
}

// Round 2
// 3540.080 us; speedup vs baseline: 1.5554x; 1.5554x over previous
//
#include <hip/hip_runtime.h>
#include <hip/hip_bf16.h>

// B=64, P=196, T=30, E=D=A=ENC=512, V=30000
#define BB 64
#define PP 196
#define TT 30
#define DD 512
#define VV 30000
#define VPAD 30080           // 235*128
#define MROWS 1856           // 29*64
#define MPAD 1920            // 15*128
#define NBLK 64              // persistent kernel grid

typedef __attribute__((ext_vector_type(8))) short short8;
typedef __attribute__((ext_vector_type(4))) float f32x4;

__device__ __forceinline__ unsigned short f2bf(float f) {
    unsigned int u = __float_as_uint(f);
    unsigned int r = u + 0x7FFFu + ((u >> 16) & 1u);
    return (unsigned short)(r >> 16);
}
__device__ __forceinline__ float bf2f(unsigned short u) {
    return __uint_as_float(((unsigned int)u) << 16);
}
__device__ __forceinline__ float sigf(float x) { return 1.f / (1.f + __expf(-x)); }
__device__ __forceinline__ float tanh_fast(float x) { return 1.f - 2.f / (1.f + __expf(2.f * x)); }

// ---------------- cast fp32 -> bf16 ----------------
__global__ __launch_bounds__(256) void k_cast(const float* __restrict__ in,
                                              unsigned short* __restrict__ out, int n) {
    int i = blockIdx.x * 256 + threadIdx.x;
    int stride = gridDim.x * 256;
    for (; i < n; i += stride) out[i] = f2bf(in[i]);
}

// ------- transpose fp32 [R][C] -> bf16 out[outr][ostride] at +ooff, zero-fill C..Cpad -------
__global__ __launch_bounds__(256) void k_transpose_cast(const float* __restrict__ in,
                                                        unsigned short* __restrict__ out,
                                                        int R, int C, int Cpad, int ostride, int ooff) {
    __shared__ float tile[32][33];
    int tx = threadIdx.x & 31, ty = threadIdx.x >> 5;  // 32 x 8
    int c0 = blockIdx.x * 32, r0 = blockIdx.y * 32;
#pragma unroll
    for (int i = 0; i < 4; ++i) {
        int r = r0 + ty + i * 8, c = c0 + tx;
        tile[ty + i * 8][tx] = (c < C) ? in[(size_t)r * C + c] : 0.f;
    }
    __syncthreads();
#pragma unroll
    for (int i = 0; i < 4; ++i) {
        int outr = c0 + ty + i * 8, outc = r0 + tx;
        if (outr < Cpad) out[(size_t)outr * ostride + ooff + outc] = f2bf(tile[tx][ty + i * 8]);
    }
}

// ---------------- zero out[:, 0, :] ----------------
__global__ __launch_bounds__(256) void k_zero0(float* __restrict__ out) {
    int i = blockIdx.x * 256 + threadIdx.x;  // 64*30000
    int b = i / VV, v = i - b * VV;
    out[(size_t)b * (TT * VV) + v] = 0.f;
}

// ---------------- init h0 (bf16 into A_step), c0 (fp32), zero barrier ----------------
__global__ __launch_bounds__(256) void k_init(const float* __restrict__ pooled,
                                              const float* __restrict__ Wh, const float* __restrict__ bh,
                                              const float* __restrict__ Wc, const float* __restrict__ bc,
                                              unsigned short* __restrict__ A_step,
                                              float* __restrict__ cbuf, int* __restrict__ bar) {
    int b = blockIdx.x >> 1, which = blockIdx.x & 1, t = threadIdx.x;
    if (blockIdx.x == 0 && t < 64) bar[t] = 0;
    const float* W = which ? Wc : Wh;
    const float* bias = which ? bc : bh;
    const float* pr = pooled + b * DD;
    float a0 = 0.f, a1 = 0.f;
#pragma unroll 4
    for (int k = 0; k < DD; ++k) {
        float pv = pr[k];
        a0 += pv * W[k * DD + t];
        a1 += pv * W[k * DD + t + 256];
    }
    float v0 = tanh_fast(a0 + bias[t]);
    float v1 = tanh_fast(a1 + bias[t + 256]);
    if (which == 0) {
        A_step[b * 1536 + 1024 + t] = f2bf(v0);
        A_step[b * 1536 + 1024 + t + 256] = f2bf(v1);
    } else {
        cbuf[b * DD + t] = v0;
        cbuf[b * DD + t + 256] = v1;
    }
}

// -------- device-scope grid barrier (all NBLK blocks resident: grid<=CUs, 1 block/CU) --------
__device__ __forceinline__ void gbar(int* bar) {
    __syncthreads();
    if (threadIdx.x == 0) {
        int* cnt = bar;
        int* gen = bar + 32;
        int g = __hip_atomic_load(gen, __ATOMIC_RELAXED, __HIP_MEMORY_SCOPE_AGENT);
        int a = __hip_atomic_fetch_add(cnt, 1, __ATOMIC_ACQ_REL, __HIP_MEMORY_SCOPE_AGENT);
        if (a == NBLK - 1) {
            __hip_atomic_store(cnt, 0, __ATOMIC_RELAXED, __HIP_MEMORY_SCOPE_AGENT);
            __hip_atomic_store(gen, g + 1, __ATOMIC_RELEASE, __HIP_MEMORY_SCOPE_AGENT);
        } else {
            while (__hip_atomic_load(gen, __ATOMIC_ACQUIRE, __HIP_MEMORY_SCOPE_AGENT) == g)
                __builtin_amdgcn_s_sleep(2);
        }
    }
    __syncthreads();
}

// ---------------- persistent recurrence kernel: 29 steps, 3 grid syncs/step ----------------
__global__ __launch_bounds__(256, 1) void k_recur(
    const unsigned short* __restrict__ ep,    // [64*196][512] bf16 enc_proj
    const unsigned short* __restrict__ fb,    // [64*196][512] bf16 feats
    const unsigned short* __restrict__ WdbT,  // [1024][512]  rows: [Wd cols | Wbeta cols]
    const unsigned short* __restrict__ WT,    // [2048][1536] rows j: k<1024 W_ih, else W_hh
    const float* __restrict__ bd,
    const float* __restrict__ bbeta,
    const float* __restrict__ wfv,
    const int* __restrict__ caps,
    const float* __restrict__ emb,
    const float* __restrict__ b_ih,
    const float* __restrict__ b_hh,
    unsigned short* __restrict__ A_step,      // [64][1536] bf16: x(1024) | h(512)
    float* __restrict__ cbuf,                 // [64][512] fp32
    float* __restrict__ decp,                 // [64][512] fp32
    float* __restrict__ betap,                // [64][512] fp32
    unsigned short* __restrict__ hb,          // [29*64][512] bf16
    int* __restrict__ bar) {

    const int blk = blockIdx.x, t = threadIdx.x;
    const int lane = t & 63, wave = t >> 6;
    const int r16 = lane & 15, kg = lane >> 4;
    const int swz = kg ^ ((r16 >> 1) & 3);

    __shared__ unsigned short As[64 * 32];
    __shared__ unsigned short Bs[64 * 32];
    __shared__ float dec_s[DD];
    __shared__ float wf_s[DD];
    __shared__ float sc_s[256];
    __shared__ float red_s[256];

    const short8* As8 = (const short8*)As;
    const short8* Bs8 = (const short8*)Bs;
    const int srow = t >> 2, scs = t & 3;
    const int scsrc = scs ^ ((srow >> 1) & 3);

    for (int ts = 1; ts < TT; ++ts) {
        // ===== Phase A (blocks 0..15): [dec|beta] = h @ [Wd|Wb]  (M=64,N=64/blk,K=512) =====
        if (blk < 16) {
            const int n0 = blk * 64;
            f32x4 acc[4];
#pragma unroll
            for (int j = 0; j < 4; ++j) acc[j] = {0.f, 0.f, 0.f, 0.f};
            for (int k0 = 0; k0 < 512; k0 += 32) {
                ((uint4*)As)[t] = *(const uint4*)(A_step + srow * 1536 + 1024 + k0 + scsrc * 8);
                ((uint4*)Bs)[t] = *(const uint4*)(WdbT + (size_t)(n0 + srow) * 512 + k0 + scsrc * 8);
                __syncthreads();
                short8 af = As8[(wave * 16 + r16) * 4 + swz];
#pragma unroll
                for (int j = 0; j < 4; ++j) {
                    short8 bfr = Bs8[(j * 16 + r16) * 4 + swz];
                    acc[j] = __builtin_amdgcn_mfma_f32_16x16x32_bf16(af, bfr, acc[j], 0, 0, 0);
                }
                __syncthreads();
            }
#pragma unroll
            for (int j = 0; j < 4; ++j) {
                int col = n0 + j * 16 + r16;
#pragma unroll
                for (int r = 0; r < 4; ++r) {
                    int b = wave * 16 + kg * 4 + r;
                    float v = acc[j][r];
                    if (col < 512) decp[b * 512 + col] = v + bd[col];
                    else betap[b * 512 + (col - 512)] = sigf(v + bbeta[col - 512]);
                }
            }
        }
        gbar(bar);

        // ===== Phase B (all 64 blocks, one per b): attention + x assembly =====
        {
            const int b = blk;
            dec_s[t] = decp[b * 512 + t];
            dec_s[t + 256] = decp[b * 512 + t + 256];
            wf_s[t] = wfv[t];
            wf_s[t + 256] = wfv[t + 256];
            __syncthreads();
            const unsigned short* epb = ep + (size_t)(b * PP) * 512;
            for (int p = wave; p < PP; p += 4) {
                uint4 pk = *(const uint4*)(epb + p * 512 + lane * 8);
                const unsigned short* pu = (const unsigned short*)&pk;
                float s = 0.f;
#pragma unroll
                for (int j = 0; j < 8; ++j) {
                    int a = lane * 8 + j;
                    float v = bf2f(pu[j]) + dec_s[a];
                    s += tanh_fast(v) * wf_s[a];
                }
#pragma unroll
                for (int off = 32; off; off >>= 1) s += __shfl_xor(s, off);
                if (lane == 0) sc_s[p] = s;
            }
            __syncthreads();
            float sv = (t < PP) ? sc_s[t] : -1e30f;
            red_s[t] = sv;
            __syncthreads();
            for (int off = 128; off; off >>= 1) {
                if (t < off) red_s[t] = fmaxf(red_s[t], red_s[t + off]);
                __syncthreads();
            }
            float mx = red_s[0];
            __syncthreads();
            float e = (t < PP) ? __expf(sv - mx) : 0.f;
            red_s[t] = e;
            __syncthreads();
            for (int off = 128; off; off >>= 1) {
                if (t < off) red_s[t] += red_s[t + off];
                __syncthreads();
            }
            float denom = red_s[0];
            __syncthreads();
            if (t < PP) sc_s[t] = e / denom;
            __syncthreads();
            const unsigned short* fbb = fb + (size_t)(b * PP) * 512;
            float c0 = 0.f, c1 = 0.f;
#pragma unroll 4
            for (int p = 0; p < PP; ++p) {
                float a = sc_s[p];
                c0 += a * bf2f(fbb[p * 512 + t]);
                c1 += a * bf2f(fbb[p * 512 + t + 256]);
            }
            float g0 = betap[b * 512 + t], g1 = betap[b * 512 + t + 256];
            int tok = caps[b * TT + (ts - 1)];
            const float* er = emb + (size_t)tok * 512;
            unsigned short* xr = A_step + b * 1536;
            xr[t] = f2bf(er[t]);
            xr[t + 256] = f2bf(er[t + 256]);
            xr[512 + t] = f2bf(g0 * c0);
            xr[768 + t] = f2bf(g1 * c1);
        }
        gbar(bar);

        // ===== Phase C (blocks 0..31): gates GEMM (M=64,N=16x4gates,K=1536) + LSTM pointwise =====
        if (blk < 32) {
            const int d0 = blk * 16;
            f32x4 acc[4];
#pragma unroll
            for (int g = 0; g < 4; ++g) acc[g] = {0.f, 0.f, 0.f, 0.f};
            for (int k0 = 0; k0 < 1536; k0 += 32) {
                ((uint4*)As)[t] = *(const uint4*)(A_step + srow * 1536 + k0 + scsrc * 8);
                int j = ((srow >> 4) << 9) + d0 + (srow & 15);
                ((uint4*)Bs)[t] = *(const uint4*)(WT + (size_t)j * 1536 + k0 + scsrc * 8);
                __syncthreads();
                short8 af = As8[(wave * 16 + r16) * 4 + swz];
#pragma unroll
                for (int g = 0; g < 4; ++g) {
                    short8 bfr = Bs8[(g * 16 + r16) * 4 + swz];
                    acc[g] = __builtin_amdgcn_mfma_f32_16x16x32_bf16(af, bfr, acc[g], 0, 0, 0);
                }
                __syncthreads();
            }
            int d = d0 + r16;
            float bi_ = b_ih[d] + b_hh[d];
            float bf_ = b_ih[d + 512] + b_hh[d + 512];
            float bg_ = b_ih[d + 1024] + b_hh[d + 1024];
            float bo_ = b_ih[d + 1536] + b_hh[d + 1536];
#pragma unroll
            for (int r = 0; r < 4; ++r) {
                int b = wave * 16 + kg * 4 + r;
                float gi = sigf(acc[0][r] + bi_);
                float gf = sigf(acc[1][r] + bf_);
                float gg = tanh_fast(acc[2][r] + bg_);
                float go = sigf(acc[3][r] + bo_);
                float cn = gf * cbuf[b * 512 + d] + gi * gg;
                float hn = go * tanh_fast(cn);
                cbuf[b * 512 + d] = cn;
                unsigned short hbf = f2bf(hn);
                A_step[b * 1536 + 1024 + d] = hbf;
                hb[(size_t)((ts - 1) * 64 + b) * 512 + d] = hbf;
            }
        }
        gbar(bar);
    }
}

// ---------------- bf16 MFMA GEMM: C = A[M][512] * Bt[N][512]^T (+bias) ----------------
// MODE 0: enc_proj -> bf16 C[m][512], bias be_att (M=12544, N=512, exact tiles)
// MODE 1: vocab    -> scatter fp32 C[b][t+1][v], bias b_fc, guards (M=1920 pad, N=30080 pad)
template <int MODE>
__global__ __launch_bounds__(256) void gemm_mfma(const unsigned short* __restrict__ A,
                                                 const unsigned short* __restrict__ Bt,
                                                 const float* __restrict__ bias,
                                                 void* __restrict__ Cv) {
    constexpr int K = 512;
    __shared__ unsigned short As[128 * 32];
    __shared__ unsigned short Bs[128 * 32];
    const int t = threadIdx.x;
    const int m0 = blockIdx.y * 128;
    const int n0 = blockIdx.x * 128;
    const int lane = t & 63, wave = t >> 6;
    const int wm = wave >> 1, wn = wave & 1;
    const int r16 = lane & 15, kg = lane >> 4;
    const int swz = kg ^ ((r16 >> 1) & 3);

    f32x4 acc[4][4];
#pragma unroll
    for (int i = 0; i < 4; ++i)
#pragma unroll
        for (int j = 0; j < 4; ++j) acc[i][j] = {0.f, 0.f, 0.f, 0.f};

    const short8* As8 = (const short8*)As;
    const short8* Bs8 = (const short8*)Bs;

    for (int k0 = 0; k0 < K; k0 += 32) {
#pragma unroll
        for (int i = 0; i < 2; ++i) {
            int u = t + i * 256;
            int row = u >> 2, cs = u & 3;
            int csrc = cs ^ ((row >> 1) & 3);
            ((uint4*)As)[u] = *(const uint4*)(A + (size_t)(m0 + row) * K + k0 + csrc * 8);
            ((uint4*)Bs)[u] = *(const uint4*)(Bt + (size_t)(n0 + row) * K + k0 + csrc * 8);
        }
        __syncthreads();
        short8 af[4], bfr[4];
#pragma unroll
        for (int i = 0; i < 4; ++i) af[i] = As8[(wm * 64 + i * 16 + r16) * 4 + swz];
#pragma unroll
        for (int j = 0; j < 4; ++j) bfr[j] = Bs8[(wn * 64 + j * 16 + r16) * 4 + swz];
#pragma unroll
        for (int i = 0; i < 4; ++i)
#pragma unroll
            for (int j = 0; j < 4; ++j)
                acc[i][j] = __builtin_amdgcn_mfma_f32_16x16x32_bf16(af[i], bfr[j], acc[i][j], 0, 0, 0);
        __syncthreads();
    }

#pragma unroll
    for (int i = 0; i < 4; ++i) {
#pragma unroll
        for (int j = 0; j < 4; ++j) {
            int colg = n0 + wn * 64 + j * 16 + r16;
            float bv;
            if (MODE == 0) bv = bias[colg];
            else bv = (colg < VV) ? bias[colg] : 0.f;
#pragma unroll
            for (int r = 0; r < 4; ++r) {
                int rowg = m0 + wm * 64 + i * 16 + kg * 4 + r;
                float v = acc[i][j][r] + bv;
                if (MODE == 0) {
                    ((unsigned short*)Cv)[(size_t)rowg * 512 + colg] = f2bf(v);
                } else {
                    if (rowg < MROWS && colg < VV) {
                        int tt = rowg >> 6, bb2 = rowg & 63;
                        ((float*)Cv)[(size_t)bb2 * (TT * VV) + (size_t)(tt + 1) * VV + colg] = v;
                    }
                }
            }
        }
    }
}

extern "C" void kernel_launch(void* const* d_in, const int* in_sizes, int n_in,
                              void* d_out, int out_size, void* d_ws, size_t ws_size,
                              hipStream_t stream) {
    const float* feats   = (const float*)d_in[0];
    const float* pooled  = (const float*)d_in[1];
    const int*   caps    = (const int*)d_in[2];
    const float* We      = (const float*)d_in[3];
    const float* be      = (const float*)d_in[4];
    const float* Wd      = (const float*)d_in[5];
    const float* bd      = (const float*)d_in[6];
    const float* wfv     = (const float*)d_in[7];
    const float* emb     = (const float*)d_in[9];
    const float* W_ih    = (const float*)d_in[10];
    const float* W_hh    = (const float*)d_in[11];
    const float* b_ih    = (const float*)d_in[12];
    const float* b_hh    = (const float*)d_in[13];
    const float* W_inh   = (const float*)d_in[14];
    const float* b_inh   = (const float*)d_in[15];
    const float* W_inc   = (const float*)d_in[16];
    const float* b_inc   = (const float*)d_in[17];
    const float* Wfc     = (const float*)d_in[18];
    const float* bfc     = (const float*)d_in[19];
    const float* Wbeta   = (const float*)d_in[20];
    const float* bbeta   = (const float*)d_in[21];
    float* out = (float*)d_out;

    char* ws = (char*)d_ws;
    size_t off = 0;
    auto alloc = [&](size_t bytes) -> char* {
        char* p = ws + off;
        off += (bytes + 255) & ~(size_t)255;
        return p;
    };
    unsigned short* ep_bf = (unsigned short*)alloc((size_t)12544 * 512 * 2);  // enc_proj bf16
    unsigned short* fb    = (unsigned short*)alloc((size_t)12544 * 512 * 2);  // feats bf16
    unsigned short* WeT   = (unsigned short*)alloc((size_t)512 * 512 * 2);    // We^T
    unsigned short* WfcT  = (unsigned short*)alloc((size_t)VPAD * 512 * 2);   // Wfc^T (padded)
    unsigned short* WdbT  = (unsigned short*)alloc((size_t)1024 * 512 * 2);   // [Wd|Wb]^T
    unsigned short* WT    = (unsigned short*)alloc((size_t)2048 * 1536 * 2);  // [W_ih;W_hh]^T
    unsigned short* hb    = (unsigned short*)alloc((size_t)MPAD * 512 * 2);   // h_all bf16
    unsigned short* A_step= (unsigned short*)alloc((size_t)64 * 1536 * 2);    // [x|h] bf16
    float*          cbuf  = (float*)alloc((size_t)64 * 512 * 4);
    float*          decp  = (float*)alloc((size_t)64 * 512 * 4);
    float*          betap = (float*)alloc((size_t)64 * 512 * 4);
    int*            bar   = (int*)alloc(256);
    (void)ws_size; (void)in_sizes; (void)n_in; (void)out_size;

    // precompute
    k_cast<<<2048, 256, 0, stream>>>(feats, fb, 12544 * 512);
    k_transpose_cast<<<dim3(16, 16), 256, 0, stream>>>(We, WeT, 512, 512, 512, 512, 0);
    k_transpose_cast<<<dim3(940, 16), 256, 0, stream>>>(Wfc, WfcT, 512, VV, VPAD, 512, 0);
    k_transpose_cast<<<dim3(16, 16), 256, 0, stream>>>(Wd, WdbT, 512, 512, 512, 512, 0);
    k_transpose_cast<<<dim3(16, 16), 256, 0, stream>>>(Wbeta, WdbT + 512 * 512, 512, 512, 512, 512, 0);
    k_transpose_cast<<<dim3(64, 32), 256, 0, stream>>>(W_ih, WT, 1024, 2048, 2048, 1536, 0);
    k_transpose_cast<<<dim3(64, 16), 256, 0, stream>>>(W_hh, WT, 512, 2048, 2048, 1536, 1024);
    k_init<<<128, 256, 0, stream>>>(pooled, W_inh, b_inh, W_inc, b_inc, A_step, cbuf, bar);
    gemm_mfma<0><<<dim3(4, 98), 256, 0, stream>>>(fb, WeT, be, ep_bf);
    k_zero0<<<7500, 256, 0, stream>>>(out);

    // persistent recurrence (29 steps, 3 grid barriers per step)
    k_recur<<<NBLK, 256, 0, stream>>>(ep_bf, fb, WdbT, WT, bd, bbeta, wfv, caps, emb,
                                      b_ih, b_hh, A_step, cbuf, decp, betap, hb, bar);

    // batched vocab projection for all 29 steps
    gemm_mfma<1><<<dim3(235, 15), 256, 0, stream>>>(hb, WfcT, bfc, out);
}